// Round 1
// baseline (823.258 us; speedup 1.0000x reference)
//
#include <hip/hip_runtime.h>
#include <stdint.h>

#define EMBED 1024
#define TOKLEN 100
#define TOKDIM 256
#define MLPD 128
#define MROWS 32768
#define KEXT 1152   // 1024 body + 128 attn (100 real + 28 zero)

typedef float f32x4 __attribute__((ext_vector_type(4)));
typedef __bf16 bf16x8 __attribute__((ext_vector_type(8)));

__device__ __forceinline__ unsigned short f2bf(float f) {
  unsigned int u = __float_as_uint(f);
  u += 0x7fffu + ((u >> 16) & 1);   // RNE
  return (unsigned short)(u >> 16);
}
__device__ __forceinline__ float bf2f(unsigned short h) {
  return __uint_as_float(((unsigned int)h) << 16);
}
__device__ __forceinline__ void async16(const void* g, void* l) {
  __builtin_amdgcn_global_load_lds(
      (const __attribute__((address_space(1))) unsigned int*)g,
      (__attribute__((address_space(3))) unsigned int*)l, 16, 0, 0);
}

// ---------------- small precompute chain (f32) ----------------

// G[c][j] = gelu(B[layer][c][:] . Wd[j][:] + bd[j]),  (1024 x 128), K=256
__global__ void k_gelu(const float* __restrict__ B, const int* __restrict__ layer,
                       const float* __restrict__ Wd, const float* __restrict__ bd,
                       float* __restrict__ G) {
  int idx = blockIdx.x * 256 + threadIdx.x;      // 0..131071
  int c = idx >> 7, j = idx & 127;
  const float* bl = B + ((size_t)layer[0] * EMBED + c) * TOKDIM;
  const float* wd = Wd + (size_t)j * TOKDIM;
  float a0 = 0.f, a1 = 0.f, a2 = 0.f, a3 = 0.f;
  for (int k = 0; k < TOKDIM; k += 4) {
    float4 a = *(const float4*)(bl + k);
    float4 b = *(const float4*)(wd + k);
    a0 += a.x * b.x; a1 += a.y * b.y; a2 += a.z * b.z; a3 += a.w * b.w;
  }
  float v = a0 + a1 + a2 + a3 + bd[j];
  G[idx] = 0.5f * v * (1.f + erff(v * 0.70710678118654752440f));
}

// AG[m][j] = A0[m][:] . G[:][j]  (100 x 128, K=1024); asum[m] = sum(A0[m][:])
__global__ void k_ag(const float* __restrict__ A, const float* __restrict__ G,
                     float* __restrict__ AG, float* __restrict__ asum) {
  int m = blockIdx.x, j = threadIdx.x;           // 100 blocks x 128 thr
  const float* a = A + (size_t)m * EMBED;
  float acc = 0.f, s = 0.f;
  for (int c = 0; c < EMBED; ++c) acc += a[c] * G[(size_t)c * MLPD + j];
  AG[(size_t)m * MLPD + j] = acc;
  for (int c = j; c < EMBED; c += 128) s += a[c];
  __shared__ float red[128];
  red[j] = s; __syncthreads();
  for (int w = 64; w > 0; w >>= 1) { if (j < w) red[j] += red[j + w]; __syncthreads(); }
  if (j == 0) asum[m] = red[0];
}

// tokens[m][e] = AG[m][:] . Wu[e][:] + asum[m]*bu[e]; tokbf padded to 128 rows
__global__ void k_tokens(const float* __restrict__ AG, const float* __restrict__ asum,
                         const float* __restrict__ Wu, const float* __restrict__ bu,
                         float* __restrict__ tokens, unsigned short* __restrict__ tokbf) {
  int m = blockIdx.x, t = threadIdx.x;           // 128 blocks x 256 thr
  if (m >= TOKLEN) {
    #pragma unroll
    for (int i = 0; i < 4; ++i) tokbf[(size_t)m * EMBED + t * 4 + i] = 0;
    return;
  }
  __shared__ float ag[MLPD];
  __shared__ float as_s;
  if (t < MLPD) ag[t] = AG[(size_t)m * MLPD + t];
  if (t == 0) as_s = asum[m];
  __syncthreads();
  #pragma unroll
  for (int i = 0; i < 4; ++i) {
    int e = t * 4 + i;
    const float* wu = Wu + (size_t)e * MLPD;
    float a0 = 0.f, a1 = 0.f, a2 = 0.f, a3 = 0.f;
    for (int j = 0; j < MLPD; j += 4) {
      float4 w = *(const float4*)(wu + j);
      a0 += w.x * ag[j]; a1 += w.y * ag[j + 1]; a2 += w.z * ag[j + 2]; a3 += w.w * ag[j + 3];
    }
    float v = a0 + a1 + a2 + a3 + as_s * bu[e];
    tokens[(size_t)m * EMBED + e] = v;
    tokbf[(size_t)m * EMBED + e] = f2bf(v);
  }
}

// tfeat[m][:] = tokens[m][:] @ Wt.T + bt ; Bt[e][1024+m] = bf16(tfeat[m][:] . Wf[e][:])
__global__ void k_tfeat(const float* __restrict__ tokens, const float* __restrict__ Wt,
                        const float* __restrict__ bt, const float* __restrict__ Wf,
                        unsigned short* __restrict__ Bt) {
  int m = blockIdx.x, t = threadIdx.x;           // 100 blocks x 256 thr
  __shared__ float tk[EMBED];
  __shared__ float tf[EMBED];
  for (int i = t; i < EMBED; i += 256) tk[i] = tokens[(size_t)m * EMBED + i];
  __syncthreads();
  #pragma unroll
  for (int i = 0; i < 4; ++i) {
    int e = t + i * 256;
    const float* w = Wt + (size_t)e * EMBED;
    float a0 = 0.f, a1 = 0.f, a2 = 0.f, a3 = 0.f, a4 = 0.f, a5 = 0.f, a6 = 0.f, a7 = 0.f;
    for (int k = 0; k < EMBED; k += 8) {
      float4 w0 = *(const float4*)(w + k);
      float4 w1 = *(const float4*)(w + k + 4);
      a0 += w0.x * tk[k];     a1 += w0.y * tk[k + 1];
      a2 += w0.z * tk[k + 2]; a3 += w0.w * tk[k + 3];
      a4 += w1.x * tk[k + 4]; a5 += w1.y * tk[k + 5];
      a6 += w1.z * tk[k + 6]; a7 += w1.w * tk[k + 7];
    }
    tf[e] = a0 + a1 + a2 + a3 + a4 + a5 + a6 + a7 + bt[e];
  }
  __syncthreads();
  #pragma unroll
  for (int i = 0; i < 4; ++i) {
    int e = t + i * 256;
    const float* w = Wf + (size_t)e * EMBED;
    float a0 = 0.f, a1 = 0.f, a2 = 0.f, a3 = 0.f, a4 = 0.f, a5 = 0.f, a6 = 0.f, a7 = 0.f;
    for (int k = 0; k < EMBED; k += 8) {
      float4 w0 = *(const float4*)(w + k);
      float4 w1 = *(const float4*)(w + k + 4);
      a0 += w0.x * tf[k];     a1 += w0.y * tf[k + 1];
      a2 += w0.z * tf[k + 2]; a3 += w0.w * tf[k + 3];
      a4 += w1.x * tf[k + 4]; a5 += w1.y * tf[k + 5];
      a6 += w1.z * tf[k + 6]; a7 += w1.w * tf[k + 7];
    }
    Bt[(size_t)e * KEXT + 1024 + m] = f2bf(a0 + a1 + a2 + a3 + a4 + a5 + a6 + a7);
  }
}

// Bt[e][0..1023] = bf16(Wf[e][:]); Bt[e][1124..1151] = 0
__global__ void k_wfcvt(const float* __restrict__ Wf, unsigned short* __restrict__ Bt) {
  int e = blockIdx.x, t = threadIdx.x;           // 1024 blocks x 256 thr
  float4 v = *(const float4*)(Wf + (size_t)e * EMBED + t * 4);
  unsigned short* dst = Bt + (size_t)e * KEXT + t * 4;
  dst[0] = f2bf(v.x); dst[1] = f2bf(v.y); dst[2] = f2bf(v.z); dst[3] = f2bf(v.w);
  if (t < 28) Bt[(size_t)e * KEXT + 1124 + t] = 0;
}

__global__ void k_cls(const float* __restrict__ x, float* __restrict__ out) {
  int i = blockIdx.x * 256 + threadIdx.x;        // 8 blocks: 8192 floats
  ((float4*)out)[i] = ((const float4*)x)[i];
}

// ---------------- attention scores + softmax -> A_ext ----------------
// A_ext[r][0..1023] = bf16(body[r][:]); A_ext[r][1024+m] = attn[r][m] (0 for m>=100)
__global__ void __launch_bounds__(256) k_attn(const float* __restrict__ x,
                                              const unsigned short* __restrict__ tokbf,
                                              unsigned short* __restrict__ Aext) {
  __shared__ unsigned short smem[128 * 72 + 128 * 64];  // As(padded 72) + Ts
  unsigned short* As = smem;
  unsigned short* Ts = smem + 128 * 72;
  const int tid = threadIdx.x;
  const int wave = tid >> 6, lane = tid & 63;
  const int l15 = lane & 15, quad = lane >> 4;
  const int srow = lane >> 3, schunk = lane & 7;
  const int row0 = blockIdx.x * 128;
  const int trow = tid >> 1, thalf = tid & 1;
  const float* body = x + 8 * EMBED;

  f32x4 acc[2][8];
  const f32x4 zero = {0.f, 0.f, 0.f, 0.f};
  #pragma unroll
  for (int i = 0; i < 2; ++i)
    #pragma unroll
    for (int j = 0; j < 8; ++j) acc[i][j] = zero;

  for (int kt = 0; kt < 16; ++kt) {
    const int k0 = kt * 64;
    #pragma unroll
    for (int i = 0; i < 4; ++i) {
      const int r = i * 32 + wave * 8;
      async16(tokbf + (size_t)(r + srow) * EMBED + k0 + schunk * 8, &Ts[r * 64]);
    }
    const float* gx = body + (size_t)(row0 + trow) * EMBED + k0 + thalf * 32;
    float4 v[8];
    #pragma unroll
    for (int q = 0; q < 8; ++q) v[q] = *(const float4*)(gx + q * 4);
    unsigned int pk[16];
    #pragma unroll
    for (int q = 0; q < 8; ++q) {
      pk[q * 2]     = (unsigned int)f2bf(v[q].x) | ((unsigned int)f2bf(v[q].y) << 16);
      pk[q * 2 + 1] = (unsigned int)f2bf(v[q].z) | ((unsigned int)f2bf(v[q].w) << 16);
    }
    unsigned int* lw = (unsigned int*)&As[trow * 72 + thalf * 32];
    unsigned int* gw = (unsigned int*)(Aext + (size_t)(row0 + trow) * KEXT + k0 + thalf * 32);
    #pragma unroll
    for (int q = 0; q < 4; ++q) {
      uint4 u; u.x = pk[q*4]; u.y = pk[q*4+1]; u.z = pk[q*4+2]; u.w = pk[q*4+3];
      ((uint4*)lw)[q] = u;
      ((uint4*)gw)[q] = u;
    }
    asm volatile("s_waitcnt vmcnt(0)" ::: "memory");
    __syncthreads();
    #pragma unroll
    for (int ks = 0; ks < 2; ++ks) {
      bf16x8 a[2], b[8];
      #pragma unroll
      for (int i = 0; i < 2; ++i)
        a[i] = *(const bf16x8*)&As[(wave * 32 + i * 16 + l15) * 72 + ks * 32 + quad * 8];
      #pragma unroll
      for (int j = 0; j < 8; ++j)
        b[j] = *(const bf16x8*)&Ts[(j * 16 + l15) * 64 + ks * 32 + quad * 8];
      #pragma unroll
      for (int i = 0; i < 2; ++i)
        #pragma unroll
        for (int j = 0; j < 8; ++j)
          acc[i][j] = __builtin_amdgcn_mfma_f32_16x16x32_bf16(a[i], b[j], acc[i][j], 0, 0, 0);
    }
    __syncthreads();
  }

  // scores -> LDS (bf16, reuse smem), scaled by 1/sqrt(1024)
  unsigned short* Sc = smem;
  #pragma unroll
  for (int i = 0; i < 2; ++i) {
    const int rb = wave * 32 + i * 16 + quad * 4;
    #pragma unroll
    for (int j = 0; j < 8; ++j) {
      const int c = j * 16 + l15;
      #pragma unroll
      for (int r = 0; r < 4; ++r)
        Sc[(rb + r) * 128 + c] = f2bf(acc[i][j][r] * 0.03125f);
    }
  }
  __syncthreads();
  if (tid < 128) {
    unsigned short* row = Sc + tid * 128;
    float mx = -1e30f;
    for (int m = 0; m < TOKLEN; ++m) mx = fmaxf(mx, bf2f(row[m]));
    float s = 0.f;
    for (int m = 0; m < TOKLEN; ++m) s += __expf(bf2f(row[m]) - mx);
    float inv = 1.f / s;
    for (int m = 0; m < TOKLEN; ++m) row[m] = f2bf(__expf(bf2f(row[m]) - mx) * inv);
    for (int m = TOKLEN; m < 128; ++m) row[m] = 0;
  }
  __syncthreads();
  {
    const int r = tid >> 1, h = tid & 1;
    const uint4* src = (const uint4*)(Sc + r * 128 + h * 64);
    uint4* dst = (uint4*)(Aext + (size_t)(row0 + r) * KEXT + 1024 + h * 64);
    dst[0] = src[0]; dst[1] = src[1]; dst[2] = src[2]; dst[3] = src[3];
  }
}

// ---------------- main GEMM: C = A_ext(32768x1152) @ Bt(1024x1152)^T ----------------
__global__ void __launch_bounds__(256) k_main(const unsigned short* __restrict__ Aext,
                                              const unsigned short* __restrict__ Bt,
                                              const float* __restrict__ x,
                                              const float* __restrict__ bfv,
                                              const float* __restrict__ scale,
                                              float* __restrict__ out) {
  __shared__ unsigned short As[128 * 64];
  __shared__ unsigned short Bs[128 * 64];
  const int tid = threadIdx.x;
  const int wave = tid >> 6, lane = tid & 63;
  const int l15 = lane & 15, quad = lane >> 4;
  const int srow = lane >> 3, schunk = lane & 7;
  const int row0 = blockIdx.y * 128;
  const int col0 = blockIdx.x * 128;
  const int wr = (wave >> 1) * 64, wc = (wave & 1) * 64;

  f32x4 acc[4][4];
  const f32x4 zero = {0.f, 0.f, 0.f, 0.f};
  #pragma unroll
  for (int i = 0; i < 4; ++i)
    #pragma unroll
    for (int j = 0; j < 4; ++j) acc[i][j] = zero;

  for (int kt = 0; kt < 18; ++kt) {
    const int k0 = kt * 64;
    #pragma unroll
    for (int i = 0; i < 4; ++i) {
      const int r = i * 32 + wave * 8;
      async16(Aext + (size_t)(row0 + r + srow) * KEXT + k0 + schunk * 8, &As[r * 64]);
      async16(Bt   + (size_t)(col0 + r + srow) * KEXT + k0 + schunk * 8, &Bs[r * 64]);
    }
    asm volatile("s_waitcnt vmcnt(0)" ::: "memory");
    __syncthreads();
    #pragma unroll
    for (int ks = 0; ks < 2; ++ks) {
      bf16x8 a[4], b[4];
      #pragma unroll
      for (int i = 0; i < 4; ++i)
        a[i] = *(const bf16x8*)&As[(wr + i * 16 + l15) * 64 + ks * 32 + quad * 8];
      #pragma unroll
      for (int j = 0; j < 4; ++j)
        b[j] = *(const bf16x8*)&Bs[(wc + j * 16 + l15) * 64 + ks * 32 + quad * 8];
      #pragma unroll
      for (int i = 0; i < 4; ++i)
        #pragma unroll
        for (int j = 0; j < 4; ++j)
          acc[i][j] = __builtin_amdgcn_mfma_f32_16x16x32_bf16(a[i], b[j], acc[i][j], 0, 0, 0);
    }
    __syncthreads();
  }

  const float s = scale[0];
  #pragma unroll
  for (int j = 0; j < 4; ++j) {
    const int c = col0 + wc + j * 16 + l15;
    const float bfc = bfv[c];
    #pragma unroll
    for (int i = 0; i < 4; ++i) {
      const int rb = row0 + wr + i * 16 + quad * 4;
      #pragma unroll
      for (int r = 0; r < 4; ++r) {
        const size_t idx = (size_t)(rb + r + 8) * EMBED + c;
        out[idx] = x[idx] + (acc[i][j][r] + bfc) * s;
      }
    }
  }
}

extern "C" void kernel_launch(void* const* d_in, const int* in_sizes, int n_in,
                              void* d_out, int out_size, void* d_ws, size_t ws_size,
                              hipStream_t stream) {
  const float* x     = (const float*)d_in[0];
  const int*   layer = (const int*)d_in[1];
  const float* A     = (const float*)d_in[2];
  const float* B     = (const float*)d_in[3];
  const float* Wd    = (const float*)d_in[4];
  const float* bd    = (const float*)d_in[5];
  const float* Wu    = (const float*)d_in[6];
  const float* bu    = (const float*)d_in[7];
  const float* Wt    = (const float*)d_in[8];
  const float* bt    = (const float*)d_in[9];
  const float* Wf    = (const float*)d_in[10];
  const float* bf    = (const float*)d_in[11];
  const float* scale = (const float*)d_in[12];
  float* out = (float*)d_out;

  char* ws = (char*)d_ws;
  unsigned short* Aext   = (unsigned short*)(ws + 0);          // 32768*1152*2 = 75,497,472
  unsigned short* Bt_    = (unsigned short*)(ws + 75497472);   // 1024*1152*2  =  2,359,296
  unsigned short* tokbf  = (unsigned short*)(ws + 77856768);   // 128*1024*2   =    262,144
  float*          G      = (float*)(ws + 78118912);            // 1024*128*4   =    524,288
  float*          AG     = (float*)(ws + 78643200);            // 100*128*4
  float*          asum   = (float*)(ws + 78694400);            // 128*4
  float*          tokens = (float*)(ws + 78694912);            // 100*1024*4
  // total ~79.1 MB of d_ws used

  k_gelu  <<<512, 256, 0, stream>>>(B, layer, Wd, bd, G);
  k_ag    <<<100, 128, 0, stream>>>(A, G, AG, asum);
  k_tokens<<<128, 256, 0, stream>>>(AG, asum, Wu, bu, tokens, tokbf);
  k_tfeat <<<100, 256, 0, stream>>>(tokens, Wt, bt, Wf, Bt_);
  k_wfcvt <<<1024, 256, 0, stream>>>(Wf, Bt_);
  k_cls   <<<8, 256, 0, stream>>>(x, out);
  k_attn  <<<256, 256, 0, stream>>>(x, tokbf, Aext);
  k_main  <<<dim3(8, 256), 256, 0, stream>>>(Aext, Bt_, x, bf, scale, out);
}

// Round 3
// 568.867 us; speedup vs baseline: 1.4472x; 1.4472x over previous
//
#include <hip/hip_runtime.h>
#include <stdint.h>

#define EMBED 1024
#define TOKLEN 100
#define TOKDIM 256
#define MLPD 128
#define KEXT 1152   // 1024 body + 128 attn (100 real + 28 zero)

typedef float f32x4 __attribute__((ext_vector_type(4)));
typedef __bf16 bf16x8 __attribute__((ext_vector_type(8)));

__device__ __forceinline__ unsigned short f2bf(float f) {
  unsigned int u = __float_as_uint(f);
  u += 0x7fffu + ((u >> 16) & 1);   // RNE
  return (unsigned short)(u >> 16);
}
__device__ __forceinline__ float bf2f(unsigned short h) {
  return __uint_as_float(((unsigned int)h) << 16);
}
__device__ __forceinline__ void async16(const void* g, void* l) {
  __builtin_amdgcn_global_load_lds(
      (const __attribute__((address_space(1))) unsigned int*)g,
      (__attribute__((address_space(3))) unsigned int*)l, 16, 0, 0);
}

// ---------------- small precompute chain ----------------

// G[c][j] = gelu(B[layer][c][:] . Wd[j][:] + bd[j]),  (1024 x 128), K=256
__global__ void k_gelu(const float* __restrict__ B, const int* __restrict__ layer,
                       const float* __restrict__ Wd, const float* __restrict__ bd,
                       float* __restrict__ G) {
  int idx = blockIdx.x * 256 + threadIdx.x;      // 0..131071
  int c = idx >> 7, j = idx & 127;
  const float* bl = B + ((size_t)layer[0] * EMBED + c) * TOKDIM;
  const float* wd = Wd + (size_t)j * TOKDIM;
  float a0 = 0.f, a1 = 0.f, a2 = 0.f, a3 = 0.f;
  for (int k = 0; k < TOKDIM; k += 4) {
    float4 a = *(const float4*)(bl + k);
    float4 b = *(const float4*)(wd + k);
    a0 += a.x * b.x; a1 += a.y * b.y; a2 += a.z * b.z; a3 += a.w * b.w;
  }
  float v = a0 + a1 + a2 + a3 + bd[j];
  G[idx] = 0.5f * v * (1.f + erff(v * 0.70710678118654752440f));
}

// AG[m][j] = A0[m][:] . G[:][j]  (100 x 128, K=1024); asum[m] = sum(A0[m][:])
__global__ void k_ag(const float* __restrict__ A, const float* __restrict__ G,
                     float* __restrict__ AG, float* __restrict__ asum) {
  int m = blockIdx.x, j = threadIdx.x;           // 100 blocks x 128 thr
  const float* a = A + (size_t)m * EMBED;
  float acc = 0.f, s = 0.f;
  for (int c = 0; c < EMBED; ++c) acc += a[c] * G[(size_t)c * MLPD + j];
  AG[(size_t)m * MLPD + j] = acc;
  for (int c = j; c < EMBED; c += 128) s += a[c];
  __shared__ float red[128];
  red[j] = s; __syncthreads();
  for (int w = 64; w > 0; w >>= 1) { if (j < w) red[j] += red[j + w]; __syncthreads(); }
  if (j == 0) asum[m] = red[0];
}

// tokbf[m][e] = bf16(AG[m][:] . Wu[e][:] + asum[m]*bu[e]); rows >=100 zeroed
__global__ void k_tokens(const float* __restrict__ AG, const float* __restrict__ asum,
                         const float* __restrict__ Wu, const float* __restrict__ bu,
                         unsigned short* __restrict__ tokbf) {
  int m = blockIdx.x, t = threadIdx.x;           // 128 blocks x 256 thr
  if (m >= TOKLEN) {
    #pragma unroll
    for (int i = 0; i < 4; ++i) tokbf[(size_t)m * EMBED + t * 4 + i] = 0;
    return;
  }
  __shared__ float ag[MLPD];
  __shared__ float as_s;
  if (t < MLPD) ag[t] = AG[(size_t)m * MLPD + t];
  if (t == 0) as_s = asum[m];
  __syncthreads();
  #pragma unroll
  for (int i = 0; i < 4; ++i) {
    int e = t * 4 + i;
    const float* wu = Wu + (size_t)e * MLPD;
    float a0 = 0.f, a1 = 0.f, a2 = 0.f, a3 = 0.f;
    for (int j = 0; j < MLPD; j += 4) {
      float4 w = *(const float4*)(wu + j);
      a0 += w.x * ag[j]; a1 += w.y * ag[j + 1]; a2 += w.z * ag[j + 2]; a3 += w.w * ag[j + 3];
    }
    tokbf[(size_t)m * EMBED + e] = f2bf(a0 + a1 + a2 + a3 + as_s * bu[e]);
  }
}

// Bt[e][0..1023] = bf16(Wf[e][:]) (stride KEXT); wfbf[e][:] same, contiguous;
// Bt[e][1124..1151] zeroed (defensive; overwritten by k_tf2 anyway)
__global__ void k_wfcvt(const float* __restrict__ Wf, unsigned short* __restrict__ Bt,
                        unsigned short* __restrict__ wfbf) {
  int e = blockIdx.x, t = threadIdx.x;           // 1024 blocks x 256 thr
  float4 v = *(const float4*)(Wf + (size_t)e * EMBED + t * 4);
  uint2 u;
  u.x = (unsigned int)f2bf(v.x) | ((unsigned int)f2bf(v.y) << 16);
  u.y = (unsigned int)f2bf(v.z) | ((unsigned int)f2bf(v.w) << 16);
  *(uint2*)(Bt + (size_t)e * KEXT + t * 4) = u;
  *(uint2*)(wfbf + (size_t)e * EMBED + t * 4) = u;
  if (t < 28) Bt[(size_t)e * KEXT + 1124 + t] = 0;
}

// wtbf = bf16(Wt), contiguous 1024x1024
__global__ void k_wtcvt(const float* __restrict__ Wt, unsigned short* __restrict__ wtbf) {
  int idx = blockIdx.x * 256 + threadIdx.x;      // 1024 blocks x 256 thr
  float4 v = *(const float4*)(Wt + (size_t)idx * 4);
  uint2 u;
  u.x = (unsigned int)f2bf(v.x) | ((unsigned int)f2bf(v.y) << 16);
  u.y = (unsigned int)f2bf(v.z) | ((unsigned int)f2bf(v.w) << 16);
  *(uint2*)(wtbf + (size_t)idx * 4) = u;
}

// wfbt[e] = Wf[e][:] . bt[:]
__global__ void k_wfbt(const float* __restrict__ Wf, const float* __restrict__ bt,
                       float* __restrict__ wfbt) {
  int e = blockIdx.x, t = threadIdx.x;           // 1024 blocks x 256 thr
  float4 w = *(const float4*)(Wf + (size_t)e * EMBED + t * 4);
  float4 b = *(const float4*)(bt + t * 4);
  __shared__ float red[256];
  red[t] = w.x * b.x + w.y * b.y + w.z * b.z + w.w * b.w;
  __syncthreads();
  for (int s = 128; s > 0; s >>= 1) { if (t < s) red[t] += red[t + s]; __syncthreads(); }
  if (t == 0) wfbt[e] = red[0];
}

__global__ void k_cls(const float* __restrict__ x, float* __restrict__ out) {
  int i = blockIdx.x * 256 + threadIdx.x;        // 8 blocks: 8192 floats
  ((float4*)out)[i] = ((const float4*)x)[i];
}

// ---------------- tfeat path: two k_main-clone MFMA GEMMs ----------------

// k_tf1: tfeatbf(128 x 1024) = tokbf(128x1024) @ wtbf(1024x1024)^T
// grid 8 blocks over e-tiles of 128. Exact structural clone of k_main staging.
__global__ void __launch_bounds__(256) k_tf1(const unsigned short* __restrict__ tokbf,
                                             const unsigned short* __restrict__ wtbf,
                                             unsigned short* __restrict__ tfeatbf) {
  __shared__ unsigned short As[128 * 64];
  __shared__ unsigned short Bs[128 * 64];
  const int tid = threadIdx.x;
  const int wave = tid >> 6, lane = tid & 63;
  const int l15 = lane & 15, quad = lane >> 4;
  const int srow = lane >> 3, schunk = lane & 7;
  const int col0 = blockIdx.x * 128;
  const int wr = (wave >> 1) * 64, wc = (wave & 1) * 64;

  f32x4 acc[4][4];
  const f32x4 zero = {0.f, 0.f, 0.f, 0.f};
  #pragma unroll
  for (int i = 0; i < 4; ++i)
    #pragma unroll
    for (int j = 0; j < 4; ++j) acc[i][j] = zero;

  for (int kt = 0; kt < 16; ++kt) {
    const int k0 = kt * 64;
    #pragma unroll
    for (int i = 0; i < 4; ++i) {
      const int r = i * 32 + wave * 8;
      async16(tokbf + (size_t)(r + srow) * EMBED + k0 + schunk * 8, &As[r * 64]);
      async16(wtbf + (size_t)(col0 + r + srow) * EMBED + k0 + schunk * 8, &Bs[r * 64]);
    }
    asm volatile("s_waitcnt vmcnt(0)" ::: "memory");
    __syncthreads();
    #pragma unroll
    for (int ks = 0; ks < 2; ++ks) {
      bf16x8 a[4], b[4];
      #pragma unroll
      for (int i = 0; i < 4; ++i)
        a[i] = *(const bf16x8*)&As[(wr + i * 16 + l15) * 64 + ks * 32 + quad * 8];
      #pragma unroll
      for (int j = 0; j < 4; ++j)
        b[j] = *(const bf16x8*)&Bs[(wc + j * 16 + l15) * 64 + ks * 32 + quad * 8];
      #pragma unroll
      for (int i = 0; i < 4; ++i)
        #pragma unroll
        for (int j = 0; j < 4; ++j)
          acc[i][j] = __builtin_amdgcn_mfma_f32_16x16x32_bf16(a[i], b[j], acc[i][j], 0, 0, 0);
    }
    __syncthreads();
  }
  // C rows (quad*4+r) = token m; C cols (l15) = e within tile
  #pragma unroll
  for (int j = 0; j < 4; ++j) {
    const int e = col0 + wc + j * 16 + l15;
    #pragma unroll
    for (int i = 0; i < 4; ++i) {
      const int mb = wr + i * 16 + quad * 4;
      #pragma unroll
      for (int r = 0; r < 4; ++r)
        tfeatbf[(size_t)(mb + r) * EMBED + e] = f2bf(acc[i][j][r]);
    }
  }
}

// k_tf2: Bt[e][1024+m] = bf16( wfbf[e][:] . tfeatbf[m][:] + wfbt[e] )
// grid 8 blocks over e-tiles of 128. Clone of k_main staging; reads and writes
// DISTINCT buffers (wfbf vs Bt) — no aliasing.
__global__ void __launch_bounds__(256) k_tf2(const unsigned short* __restrict__ wfbf,
                                             const unsigned short* __restrict__ tfeatbf,
                                             const float* __restrict__ wfbt,
                                             unsigned short* __restrict__ Bt) {
  __shared__ unsigned short As[128 * 64];
  __shared__ unsigned short Bs[128 * 64];
  const int tid = threadIdx.x;
  const int wave = tid >> 6, lane = tid & 63;
  const int l15 = lane & 15, quad = lane >> 4;
  const int srow = lane >> 3, schunk = lane & 7;
  const int row0 = blockIdx.x * 128;
  const int wr = (wave >> 1) * 64, wc = (wave & 1) * 64;

  f32x4 acc[4][4];
  const f32x4 zero = {0.f, 0.f, 0.f, 0.f};
  #pragma unroll
  for (int i = 0; i < 4; ++i)
    #pragma unroll
    for (int j = 0; j < 4; ++j) acc[i][j] = zero;

  for (int kt = 0; kt < 16; ++kt) {
    const int k0 = kt * 64;
    #pragma unroll
    for (int i = 0; i < 4; ++i) {
      const int r = i * 32 + wave * 8;
      async16(wfbf + (size_t)(row0 + r + srow) * EMBED + k0 + schunk * 8, &As[r * 64]);
      async16(tfeatbf + (size_t)(r + srow) * EMBED + k0 + schunk * 8, &Bs[r * 64]);
    }
    asm volatile("s_waitcnt vmcnt(0)" ::: "memory");
    __syncthreads();
    #pragma unroll
    for (int ks = 0; ks < 2; ++ks) {
      bf16x8 a[4], b[4];
      #pragma unroll
      for (int i = 0; i < 4; ++i)
        a[i] = *(const bf16x8*)&As[(wr + i * 16 + l15) * 64 + ks * 32 + quad * 8];
      #pragma unroll
      for (int j = 0; j < 4; ++j)
        b[j] = *(const bf16x8*)&Bs[(wc + j * 16 + l15) * 64 + ks * 32 + quad * 8];
      #pragma unroll
      for (int i = 0; i < 4; ++i)
        #pragma unroll
        for (int j = 0; j < 4; ++j)
          acc[i][j] = __builtin_amdgcn_mfma_f32_16x16x32_bf16(a[i], b[j], acc[i][j], 0, 0, 0);
    }
    __syncthreads();
  }
  // C rows (quad*4+r) = e within tile; C cols (l15) = token m
  #pragma unroll
  for (int j = 0; j < 4; ++j) {
    const int m = wc + j * 16 + l15;
    #pragma unroll
    for (int i = 0; i < 4; ++i) {
      const int eb = row0 + wr + i * 16 + quad * 4;
      #pragma unroll
      for (int r = 0; r < 4; ++r)
        Bt[(size_t)(eb + r) * KEXT + 1024 + m] = f2bf(acc[i][j][r] + wfbt[eb + r]);
    }
  }
}

// ---------------- attention scores + softmax -> A_ext ----------------
__global__ void __launch_bounds__(256) k_attn(const float* __restrict__ x,
                                              const unsigned short* __restrict__ tokbf,
                                              unsigned short* __restrict__ Aext) {
  __shared__ unsigned short smem[128 * 72 + 128 * 64];  // As(padded 72) + Ts
  unsigned short* As = smem;
  unsigned short* Ts = smem + 128 * 72;
  const int tid = threadIdx.x;
  const int wave = tid >> 6, lane = tid & 63;
  const int l15 = lane & 15, quad = lane >> 4;
  const int srow = lane >> 3, schunk = lane & 7;
  const int row0 = blockIdx.x * 128;
  const int trow = tid >> 1, thalf = tid & 1;
  const float* body = x + 8 * EMBED;

  f32x4 acc[2][8];
  const f32x4 zero = {0.f, 0.f, 0.f, 0.f};
  #pragma unroll
  for (int i = 0; i < 2; ++i)
    #pragma unroll
    for (int j = 0; j < 8; ++j) acc[i][j] = zero;

  for (int kt = 0; kt < 16; ++kt) {
    const int k0 = kt * 64;
    #pragma unroll
    for (int i = 0; i < 4; ++i) {
      const int r = i * 32 + wave * 8;
      async16(tokbf + (size_t)(r + srow) * EMBED + k0 + schunk * 8, &Ts[r * 64]);
    }
    const float* gx = body + (size_t)(row0 + trow) * EMBED + k0 + thalf * 32;
    float4 v[8];
    #pragma unroll
    for (int q = 0; q < 8; ++q) v[q] = *(const float4*)(gx + q * 4);
    unsigned int pk[16];
    #pragma unroll
    for (int q = 0; q < 8; ++q) {
      pk[q * 2]     = (unsigned int)f2bf(v[q].x) | ((unsigned int)f2bf(v[q].y) << 16);
      pk[q * 2 + 1] = (unsigned int)f2bf(v[q].z) | ((unsigned int)f2bf(v[q].w) << 16);
    }
    unsigned int* lw = (unsigned int*)&As[trow * 72 + thalf * 32];
    unsigned int* gw = (unsigned int*)(Aext + (size_t)(row0 + trow) * KEXT + k0 + thalf * 32);
    #pragma unroll
    for (int q = 0; q < 4; ++q) {
      uint4 u; u.x = pk[q*4]; u.y = pk[q*4+1]; u.z = pk[q*4+2]; u.w = pk[q*4+3];
      ((uint4*)lw)[q] = u;
      ((uint4*)gw)[q] = u;
    }
    asm volatile("s_waitcnt vmcnt(0)" ::: "memory");
    __syncthreads();
    #pragma unroll
    for (int ks = 0; ks < 2; ++ks) {
      bf16x8 a[2], b[8];
      #pragma unroll
      for (int i = 0; i < 2; ++i)
        a[i] = *(const bf16x8*)&As[(wave * 32 + i * 16 + l15) * 72 + ks * 32 + quad * 8];
      #pragma unroll
      for (int j = 0; j < 8; ++j)
        b[j] = *(const bf16x8*)&Ts[(j * 16 + l15) * 64 + ks * 32 + quad * 8];
      #pragma unroll
      for (int i = 0; i < 2; ++i)
        #pragma unroll
        for (int j = 0; j < 8; ++j)
          acc[i][j] = __builtin_amdgcn_mfma_f32_16x16x32_bf16(a[i], b[j], acc[i][j], 0, 0, 0);
    }
    __syncthreads();
  }

  unsigned short* Sc = smem;
  #pragma unroll
  for (int i = 0; i < 2; ++i) {
    const int rb = wave * 32 + i * 16 + quad * 4;
    #pragma unroll
    for (int j = 0; j < 8; ++j) {
      const int c = j * 16 + l15;
      #pragma unroll
      for (int r = 0; r < 4; ++r)
        Sc[(rb + r) * 128 + c] = f2bf(acc[i][j][r] * 0.03125f);
    }
  }
  __syncthreads();
  if (tid < 128) {
    unsigned short* row = Sc + tid * 128;
    float mx = -1e30f;
    for (int m = 0; m < TOKLEN; ++m) mx = fmaxf(mx, bf2f(row[m]));
    float s = 0.f;
    for (int m = 0; m < TOKLEN; ++m) s += __expf(bf2f(row[m]) - mx);
    float inv = 1.f / s;
    for (int m = 0; m < TOKLEN; ++m) row[m] = f2bf(__expf(bf2f(row[m]) - mx) * inv);
    for (int m = TOKLEN; m < 128; ++m) row[m] = 0;
  }
  __syncthreads();
  {
    const int r = tid >> 1, h = tid & 1;
    const uint4* src = (const uint4*)(Sc + r * 128 + h * 64);
    uint4* dst = (uint4*)(Aext + (size_t)(row0 + r) * KEXT + 1024 + h * 64);
    dst[0] = src[0]; dst[1] = src[1]; dst[2] = src[2]; dst[3] = src[3];
  }
}

// ---------------- main GEMM: C = A_ext(32768x1152) @ Bt(1024x1152)^T ----------------
// 1D grid 2048, XCD-aware: blockIdx = ((rowtile>>3)*8 + coltile)*8 + (rowtile&7).
// Per XCD, the 8 col-tiles of one row-tile run consecutively -> 288KB A-tile
// reused from that XCD's 4MB L2.
__global__ void __launch_bounds__(256) k_main(const unsigned short* __restrict__ Aext,
                                              const unsigned short* __restrict__ Bt,
                                              const float* __restrict__ x,
                                              const float* __restrict__ bfv,
                                              const float* __restrict__ scale,
                                              float* __restrict__ out) {
  __shared__ unsigned short As[128 * 64];
  __shared__ unsigned short Bs[128 * 64];
  const int tid = threadIdx.x;
  const int wave = tid >> 6, lane = tid & 63;
  const int l15 = lane & 15, quad = lane >> 4;
  const int srow = lane >> 3, schunk = lane & 7;
  const int xcd = blockIdx.x & 7, slot = blockIdx.x >> 3;
  const int row0 = ((slot >> 3) * 8 + xcd) * 128;
  const int col0 = (slot & 7) * 128;
  const int wr = (wave >> 1) * 64, wc = (wave & 1) * 64;

  f32x4 acc[4][4];
  const f32x4 zero = {0.f, 0.f, 0.f, 0.f};
  #pragma unroll
  for (int i = 0; i < 4; ++i)
    #pragma unroll
    for (int j = 0; j < 4; ++j) acc[i][j] = zero;

  for (int kt = 0; kt < 18; ++kt) {
    const int k0 = kt * 64;
    #pragma unroll
    for (int i = 0; i < 4; ++i) {
      const int r = i * 32 + wave * 8;
      async16(Aext + (size_t)(row0 + r + srow) * KEXT + k0 + schunk * 8, &As[r * 64]);
      async16(Bt   + (size_t)(col0 + r + srow) * KEXT + k0 + schunk * 8, &Bs[r * 64]);
    }
    asm volatile("s_waitcnt vmcnt(0)" ::: "memory");
    __syncthreads();
    #pragma unroll
    for (int ks = 0; ks < 2; ++ks) {
      bf16x8 a[4], b[4];
      #pragma unroll
      for (int i = 0; i < 4; ++i)
        a[i] = *(const bf16x8*)&As[(wr + i * 16 + l15) * 64 + ks * 32 + quad * 8];
      #pragma unroll
      for (int j = 0; j < 4; ++j)
        b[j] = *(const bf16x8*)&Bs[(wc + j * 16 + l15) * 64 + ks * 32 + quad * 8];
      #pragma unroll
      for (int i = 0; i < 4; ++i)
        #pragma unroll
        for (int j = 0; j < 4; ++j)
          acc[i][j] = __builtin_amdgcn_mfma_f32_16x16x32_bf16(a[i], b[j], acc[i][j], 0, 0, 0);
    }
    __syncthreads();
  }

  const float s = scale[0];
  #pragma unroll
  for (int j = 0; j < 4; ++j) {
    const int c = col0 + wc + j * 16 + l15;
    const float bfc = bfv[c];
    #pragma unroll
    for (int i = 0; i < 4; ++i) {
      const int rb = row0 + wr + i * 16 + quad * 4;
      #pragma unroll
      for (int r = 0; r < 4; ++r) {
        const size_t idx = (size_t)(rb + r + 8) * EMBED + c;
        out[idx] = x[idx] + (acc[i][j][r] + bfc) * s;
      }
    }
  }
}

extern "C" void kernel_launch(void* const* d_in, const int* in_sizes, int n_in,
                              void* d_out, int out_size, void* d_ws, size_t ws_size,
                              hipStream_t stream) {
  const float* x     = (const float*)d_in[0];
  const int*   layer = (const int*)d_in[1];
  const float* A     = (const float*)d_in[2];
  const float* B     = (const float*)d_in[3];
  const float* Wd    = (const float*)d_in[4];
  const float* bd    = (const float*)d_in[5];
  const float* Wu    = (const float*)d_in[6];
  const float* bu    = (const float*)d_in[7];
  const float* Wt    = (const float*)d_in[8];
  const float* bt    = (const float*)d_in[9];
  const float* Wf    = (const float*)d_in[10];
  const float* bf    = (const float*)d_in[11];
  const float* scale = (const float*)d_in[12];
  float* out = (float*)d_out;

  char* ws = (char*)d_ws;
  // Aext: [0, 75,497,472). wtbf/wfbf alias its first 4MB — written by the cast
  // kernels (#4/#6), consumed by k_tf1/k_tf2 (#7/#8), then Aext is wholly
  // overwritten by k_attn (#10). No other aliasing; all other scratch lives in
  // the tail, high-water 78,961,152 B (< R1-proven 79,104,512 B).
  unsigned short* Aext    = (unsigned short*)(ws + 0);          // 32768*1152*2
  unsigned short* wtbf    = (unsigned short*)(ws + 0);          // 1024*1024*2 = 2,097,152 (alias)
  unsigned short* wfbf    = (unsigned short*)(ws + 2097152);    // 1024*1024*2 (alias)
  unsigned short* Bt_     = (unsigned short*)(ws + 75497472);   // 1024*1152*2 = 2,359,296
  unsigned short* tokbf   = (unsigned short*)(ws + 77856768);   // 128*1024*2  =   262,144
  float*          G       = (float*)(ws + 78118912);            // 1024*128*4  =   524,288
  float*          AG      = (float*)(ws + 78643200);            // 100*128*4   =    51,200
  float*          asum    = (float*)(ws + 78694400);            // 128*4
  float*          wfbt    = (float*)(ws + 78694912);            // 1024*4
  unsigned short* tfeatbf = (unsigned short*)(ws + 78699008);   // 128*1024*2  =   262,144

  k_gelu  <<<512, 256, 0, stream>>>(B, layer, Wd, bd, G);
  k_ag    <<<100, 128, 0, stream>>>(A, G, AG, asum);
  k_tokens<<<128, 256, 0, stream>>>(AG, asum, Wu, bu, tokbf);
  k_wfcvt <<<1024, 256, 0, stream>>>(Wf, Bt_, wfbf);
  k_wfbt  <<<1024, 256, 0, stream>>>(Wf, bt, wfbt);
  k_wtcvt <<<1024, 256, 0, stream>>>(Wt, wtbf);
  k_tf1   <<<8, 256, 0, stream>>>(tokbf, wtbf, tfeatbf);
  k_tf2   <<<8, 256, 0, stream>>>(wfbf, tfeatbf, wfbt, Bt_);
  k_cls   <<<8, 256, 0, stream>>>(x, out);
  k_attn  <<<256, 256, 0, stream>>>(x, tokbf, Aext);
  k_main  <<<2048, 256, 0, stream>>>(Aext, Bt_, x, bf, scale, out);
}